// Round 9
// baseline (199.612 us; speedup 1.0000x reference)
//
#include <hip/hip_runtime.h>
#include <hip/hip_bf16.h>
#include <hip/hip_fp16.h>

// Sparse gather-FFN. Conflict-model history: wave-level balancing (R8) did
// NOT move SQ_LDS_BANK_CONFLICT -> HW services ds_read_b128 in 8 phases of
// 8 consecutive lanes (octets); conflicts are per-octet bank-quad (f%8)
// collisions. R9: prepass solves per-octet edge coloring (8 lanes x 8
// groups, 16 steps): greedy max-remaining-degree with per-step used-group
// mask; counting-sorted nibble-packed per-lane lists in LDS (no scratch).
// One thread per octet-problem; main kernel identical to R8.

#define NB   32768
#define NIN  128
#define NL   8
#define NW   256
#define NK   16
#define RPB  8                        // batch rows per block (8 f16 = 16 B)
#define STORED (NIN + (NL - 1) * NW)  // 1920 features ever re-read
#define NPARAM (NL * NW * NK)         // 32768 (l,u,k) entries

typedef __fp16 fp16v2 __attribute__((ext_vector_type(2)));

__device__ __forceinline__ unsigned pk16(float a, float b) {
    fp16v2 p = __builtin_amdgcn_cvt_pkrtz(a, b);   // v_cvt_pkrtz_f16_f32
    return __builtin_bit_cast(unsigned, p);
}

__device__ __forceinline__ __half2 as_h2(unsigned u) {
    return __builtin_bit_cast(__half2, u);
}

__device__ __forceinline__ float fast_sigmoid(float x) {
    return __builtin_amdgcn_rcpf(1.0f + __expf(-x));
}

// 8 row-MACs from one 16B packed-f16 word: 4x v_pk_fma_f16
__device__ __forceinline__ void fma_feat(__half2 acc[4], __half2 w2, uint4 p) {
    acc[0] = __hfma2(as_h2(p.x), w2, acc[0]);
    acc[1] = __hfma2(as_h2(p.y), w2, acc[1]);
    acc[2] = __hfma2(as_h2(p.z), w2, acc[2]);
    acc[3] = __hfma2(as_h2(p.w), w2, acc[3]);
}

template <bool PRE>
__global__ __launch_bounds__(256, 5)
void ffn_gather_kernel(const float* __restrict__ inputs,
                       const float* __restrict__ weights,
                       const float* __restrict__ biases,
                       const int*   __restrict__ edge_idx,
                       const int*   __restrict__ idxb,   // pre-scaled byte offs
                       const unsigned* __restrict__ wpk, // packed (w,w) f16
                       float* __restrict__ out)
{
    __shared__ uint4 vals[STORED];   // vals[f] = 8 f16 rows of feature f

    const int t = threadIdx.x;                       // 0..255, unit id
    const long long row0 = (long long)blockIdx.x * RPB;
    const char* vbase = (const char*)vals;

    // ---- stage the 128 input features for 8 rows (feature-major, f16) ----
    if (t < NIN) {
        float v[RPB];
        #pragma unroll
        for (int r = 0; r < RPB; ++r) v[r] = inputs[(row0 + r) * NIN + t];
        uint4 p;
        p.x = pk16(v[0], v[1]);
        p.y = pk16(v[2], v[3]);
        p.z = pk16(v[4], v[5]);
        p.w = pk16(v[6], v[7]);
        vals[t] = p;
    }
    __syncthreads();

    // ---- layers ----
    #pragma unroll
    for (int l = 0; l < NL; ++l) {
        const int base = (l * NW + t) * NK;

        const float b = biases[l * NW + t];
        __half2 acc[4];
        const __half2 bb = __float2half2_rn(b);
        #pragma unroll
        for (int j = 0; j < 4; ++j) acc[j] = bb;

        #pragma unroll
        for (int kk = 0; kk < NK / 4; ++kk) {
            int4 o4;          // byte offsets into vals
            __half2 w0, w1, w2, w3;
            if (PRE) {
                o4 = ((const int4*)(idxb + base))[kk];
                uint4 wp = ((const uint4*)(wpk + base))[kk];
                w0 = as_h2(wp.x); w1 = as_h2(wp.y);
                w2 = as_h2(wp.z); w3 = as_h2(wp.w);
            } else {
                int4 i4 = ((const int4*)(edge_idx + base))[kk];
                o4.x = i4.x << 4; o4.y = i4.y << 4;
                o4.z = i4.z << 4; o4.w = i4.w << 4;
                float4 w4 = ((const float4*)(weights + base))[kk];
                w0 = __float2half2_rn(w4.x);
                w1 = __float2half2_rn(w4.y);
                w2 = __float2half2_rn(w4.z);
                w3 = __float2half2_rn(w4.w);
            }
            const uint4 p0 = *(const uint4*)(vbase + o4.x);
            const uint4 p1 = *(const uint4*)(vbase + o4.y);
            const uint4 p2 = *(const uint4*)(vbase + o4.z);
            const uint4 p3 = *(const uint4*)(vbase + o4.w);
            fma_feat(acc, w0, p0);
            fma_feat(acc, w1, p1);
            fma_feat(acc, w2, p2);
            fma_feat(acc, w3, p3);
        }

        float s[RPB];
        #pragma unroll
        for (int j = 0; j < 4; ++j) {
            s[2 * j + 0] = fast_sigmoid(__low2float(acc[j]));
            s[2 * j + 1] = fast_sigmoid(__high2float(acc[j]));
        }

        if (l < NL - 1) {
            uint4 p;
            p.x = pk16(s[0], s[1]);
            p.y = pk16(s[2], s[3]);
            p.z = pk16(s[4], s[5]);
            p.w = pk16(s[6], s[7]);
            vals[NIN + l * NW + t] = p;
            __syncthreads();
        } else {
            #pragma unroll
            for (int r = 0; r < RPB; ++r)
                out[(row0 + r) * NW + t] = s[r];
        }
    }
}

// ---------------------------------------------------------------------------
// Prepass v3: per-octet edge coloring. One THREAD per (layer, octet) problem:
// 8 lanes x 16 items, groups = idx%8 (bank-quad of the 16B slot). Per step,
// greedily assign each lane an item whose group is unused this step,
// preferring max remaining octet-degree (burn heavy groups early); fallback
// (stuck) also takes the heaviest. Counting-sorted per-lane item lists,
// nibble/byte-packed in u64s held in LDS -> no dynamic private arrays, no
// scratch. Commutative dot + block-invariant indices => semantics unchanged.
// ---------------------------------------------------------------------------
__global__ __launch_bounds__(64)
void prepass_kernel(const float* __restrict__ weights,
                    const int* __restrict__ edge_idx,
                    int* __restrict__ idxb,
                    unsigned* __restrict__ wpk)
{
    __shared__ unsigned long long ws_cnt[64][8];   // per lane: 8x8b group cnt
    __shared__ unsigned long long ws_st[64][8];    // per lane: 8x8b run start
    __shared__ unsigned long long ws_sorted[64][8];// per lane: 16x4b item ids

    const int t    = threadIdx.x;
    const int prob = blockIdx.x * 64 + t;          // 0..255
    const int l    = prob >> 5;                    // layer
    const int oct  = prob & 31;                    // octet within layer
    const int u0   = l * NW + oct * 8;             // first unit of octet

    // ---- load + counting-sort each lane's 16 items by group ----
    unsigned long long deg = 0;                    // octet group degrees, 8x8b
    for (int lane = 0; lane < 8; ++lane) {
        const int base = (u0 + lane) * NK;
        unsigned long long gp = 0, cnt = 0;
        for (int k = 0; k < NK; ++k) {
            const int g = edge_idx[base + k] & 7;
            gp  |= (unsigned long long)g << (4 * k);
            cnt += 1ull << (8 * g);
        }
        unsigned long long st = 0; unsigned acc = 0;
        for (int g = 0; g < 8; ++g) {
            st  |= (unsigned long long)acc << (8 * g);
            acc += (unsigned)((cnt >> (8 * g)) & 0xff);
        }
        unsigned long long sorted = 0, fill = st;
        for (int k = 0; k < NK; ++k) {
            const int g   = (int)((gp >> (4 * k)) & 7);
            const int pos = (int)((fill >> (8 * g)) & 0xff);
            sorted |= (unsigned long long)k << (4 * pos);
            fill   += 1ull << (8 * g);
        }
        ws_cnt[t][lane]    = cnt;
        ws_st[t][lane]     = st;
        ws_sorted[t][lane] = sorted;
        deg += cnt;
    }

    // ---- schedule 16 steps ----
    for (int s = 0; s < NK; ++s) {
        unsigned used = 0;
        for (int lane = 0; lane < 8; ++lane) {
            const unsigned long long cnt = ws_cnt[t][lane];
            int bg = -1, bd = -1, fg = -1, fd = -1;
            #pragma unroll
            for (int g = 0; g < 8; ++g) {
                const int c = (int)((cnt >> (8 * g)) & 0xff);
                if (c) {
                    const int d = (int)((deg >> (8 * g)) & 0xff);
                    if (d > fd) { fd = d; fg = g; }
                    if (!((used >> g) & 1) && d > bd) { bd = d; bg = g; }
                }
            }
            const int g = (bg >= 0) ? bg : fg;     // fallback = conflict step
            const unsigned long long st = ws_st[t][lane];
            const int pos = (int)((st >> (8 * g)) & 0xff);
            const int k   = (int)((ws_sorted[t][lane] >> (4 * pos)) & 0xf);
            ws_st[t][lane]  = st + (1ull << (8 * g));
            ws_cnt[t][lane] = cnt - (1ull << (8 * g));
            deg  -= 1ull << (8 * g);
            used |= 1u << g;

            const int src = (u0 + lane) * NK + k;
            const int dst = (u0 + lane) * NK + s;
            idxb[dst] = edge_idx[src] << 4;
            const float w = weights[src];
            wpk[dst] = pk16(w, w);
        }
    }
}

extern "C" void kernel_launch(void* const* d_in, const int* in_sizes, int n_in,
                              void* d_out, int out_size, void* d_ws, size_t ws_size,
                              hipStream_t stream)
{
    const float* inputs   = (const float*)d_in[0];
    const float* weights  = (const float*)d_in[1];
    const float* biases   = (const float*)d_in[2];
    const int*   edge_idx = (const int*)d_in[3];
    float* out = (float*)d_out;

    dim3 grid(NB / RPB);   // 4096
    dim3 block(NW);        // 256

    const size_t need = (size_t)NPARAM * 4 * 2;     // 256 KB
    if (ws_size >= need) {
        int*      idxb = (int*)d_ws;
        unsigned* wpk  = (unsigned*)((char*)d_ws + (size_t)NPARAM * 4);
        prepass_kernel<<<4, 64, 0, stream>>>(weights, edge_idx, idxb, wpk);
        ffn_gather_kernel<true><<<grid, block, 0, stream>>>(
            inputs, weights, biases, edge_idx, idxb, wpk, out);
    } else {
        ffn_gather_kernel<false><<<grid, block, 0, stream>>>(
            inputs, weights, biases, edge_idx, nullptr, nullptr, out);
    }
}

// Round 10
// 138.073 us; speedup vs baseline: 1.4457x; 1.4457x over previous
//
#include <hip/hip_runtime.h>
#include <hip/hip_bf16.h>
#include <hip/hip_fp16.h>

// Sparse gather-FFN. Main kernel is DS-pipe-bound at a ~77.5us plateau:
// DS busy ~64us (8192 wave ds_read_b128/CU x 12cyc base + ~23us structural
// octet conflicts) under ~13us barrier slack. R7-R9 proved schedule-order
// conflict deltas (+-15%) do NOT move dur, but the scheduling prepasses
// cost 28-67us. R10: consolidate — trivial elementwise prepass (idx<<4 +
// packed (w,w) f16, ~1-2us) + the best main kernel (f16 vals 8 rows/slot,
// v_pk_fma_f16, fast rcp-sigmoid, prepacked weights).

#define NB   32768
#define NIN  128
#define NL   8
#define NW   256
#define NK   16
#define RPB  8                        // batch rows per block (8 f16 = 16 B)
#define STORED (NIN + (NL - 1) * NW)  // 1920 features ever re-read
#define NPARAM (NL * NW * NK)         // 32768 (l,u,k) entries

typedef __fp16 fp16v2 __attribute__((ext_vector_type(2)));

__device__ __forceinline__ unsigned pk16(float a, float b) {
    fp16v2 p = __builtin_amdgcn_cvt_pkrtz(a, b);   // v_cvt_pkrtz_f16_f32
    return __builtin_bit_cast(unsigned, p);
}

__device__ __forceinline__ __half2 as_h2(unsigned u) {
    return __builtin_bit_cast(__half2, u);
}

__device__ __forceinline__ float fast_sigmoid(float x) {
    return __builtin_amdgcn_rcpf(1.0f + __expf(-x));
}

// 8 row-MACs from one 16B packed-f16 word: 4x v_pk_fma_f16
__device__ __forceinline__ void fma_feat(__half2 acc[4], __half2 w2, uint4 p) {
    acc[0] = __hfma2(as_h2(p.x), w2, acc[0]);
    acc[1] = __hfma2(as_h2(p.y), w2, acc[1]);
    acc[2] = __hfma2(as_h2(p.z), w2, acc[2]);
    acc[3] = __hfma2(as_h2(p.w), w2, acc[3]);
}

template <bool PRE>
__global__ __launch_bounds__(256, 5)
void ffn_gather_kernel(const float* __restrict__ inputs,
                       const float* __restrict__ weights,
                       const float* __restrict__ biases,
                       const int*   __restrict__ edge_idx,
                       const int*   __restrict__ idxb,   // pre-scaled byte offs
                       const unsigned* __restrict__ wpk, // packed (w,w) f16
                       float* __restrict__ out)
{
    __shared__ uint4 vals[STORED];   // vals[f] = 8 f16 rows of feature f

    const int t = threadIdx.x;                       // 0..255, unit id
    const long long row0 = (long long)blockIdx.x * RPB;
    const char* vbase = (const char*)vals;

    // ---- stage the 128 input features for 8 rows (feature-major, f16) ----
    if (t < NIN) {
        float v[RPB];
        #pragma unroll
        for (int r = 0; r < RPB; ++r) v[r] = inputs[(row0 + r) * NIN + t];
        uint4 p;
        p.x = pk16(v[0], v[1]);
        p.y = pk16(v[2], v[3]);
        p.z = pk16(v[4], v[5]);
        p.w = pk16(v[6], v[7]);
        vals[t] = p;
    }
    __syncthreads();

    // ---- layers ----
    #pragma unroll
    for (int l = 0; l < NL; ++l) {
        const int base = (l * NW + t) * NK;

        const float b = biases[l * NW + t];
        __half2 acc[4];
        const __half2 bb = __float2half2_rn(b);
        #pragma unroll
        for (int j = 0; j < 4; ++j) acc[j] = bb;

        #pragma unroll
        for (int kk = 0; kk < NK / 4; ++kk) {
            int4 o4;          // byte offsets into vals
            __half2 w0, w1, w2, w3;
            if (PRE) {
                o4 = ((const int4*)(idxb + base))[kk];
                uint4 wp = ((const uint4*)(wpk + base))[kk];
                w0 = as_h2(wp.x); w1 = as_h2(wp.y);
                w2 = as_h2(wp.z); w3 = as_h2(wp.w);
            } else {
                int4 i4 = ((const int4*)(edge_idx + base))[kk];
                o4.x = i4.x << 4; o4.y = i4.y << 4;
                o4.z = i4.z << 4; o4.w = i4.w << 4;
                float4 w4 = ((const float4*)(weights + base))[kk];
                w0 = __float2half2_rn(w4.x);
                w1 = __float2half2_rn(w4.y);
                w2 = __float2half2_rn(w4.z);
                w3 = __float2half2_rn(w4.w);
            }
            const uint4 p0 = *(const uint4*)(vbase + o4.x);
            const uint4 p1 = *(const uint4*)(vbase + o4.y);
            const uint4 p2 = *(const uint4*)(vbase + o4.z);
            const uint4 p3 = *(const uint4*)(vbase + o4.w);
            fma_feat(acc, w0, p0);
            fma_feat(acc, w1, p1);
            fma_feat(acc, w2, p2);
            fma_feat(acc, w3, p3);
        }

        float s[RPB];
        #pragma unroll
        for (int j = 0; j < 4; ++j) {
            s[2 * j + 0] = fast_sigmoid(__low2float(acc[j]));
            s[2 * j + 1] = fast_sigmoid(__high2float(acc[j]));
        }

        if (l < NL - 1) {
            uint4 p;
            p.x = pk16(s[0], s[1]);
            p.y = pk16(s[2], s[3]);
            p.z = pk16(s[4], s[5]);
            p.w = pk16(s[6], s[7]);
            vals[NIN + l * NW + t] = p;
            __syncthreads();
        } else {
            #pragma unroll
            for (int r = 0; r < RPB; ++r)
                out[(row0 + r) * NW + t] = s[r];
        }
    }
}

// trivial pre-pass: byte-offset indices + packed (w,w) f16 weights.
// (R7-R9 showed conflict-scheduling the emission order costs more in the
// prepass than it ever returns in the main kernel.)
__global__ __launch_bounds__(256)
void prepass_kernel(const float* __restrict__ weights,
                    const int* __restrict__ edge_idx,
                    int* __restrict__ idxb,
                    unsigned* __restrict__ wpk)
{
    const int i = blockIdx.x * 256 + threadIdx.x;   // 0..32767
    idxb[i] = edge_idx[i] << 4;
    const float w = weights[i];
    wpk[i] = pk16(w, w);
}

extern "C" void kernel_launch(void* const* d_in, const int* in_sizes, int n_in,
                              void* d_out, int out_size, void* d_ws, size_t ws_size,
                              hipStream_t stream)
{
    const float* inputs   = (const float*)d_in[0];
    const float* weights  = (const float*)d_in[1];
    const float* biases   = (const float*)d_in[2];
    const int*   edge_idx = (const int*)d_in[3];
    float* out = (float*)d_out;

    dim3 grid(NB / RPB);   // 4096
    dim3 block(NW);        // 256

    const size_t need = (size_t)NPARAM * 4 * 2;     // 256 KB
    if (ws_size >= need) {
        int*      idxb = (int*)d_ws;
        unsigned* wpk  = (unsigned*)((char*)d_ws + (size_t)NPARAM * 4);
        prepass_kernel<<<NPARAM / 256, 256, 0, stream>>>(weights, edge_idx,
                                                         idxb, wpk);
        ffn_gather_kernel<true><<<grid, block, 0, stream>>>(
            inputs, weights, biases, edge_idx, idxb, wpk, out);
    } else {
        ffn_gather_kernel<false><<<grid, block, 0, stream>>>(
            inputs, weights, biases, edge_idx, nullptr, nullptr, out);
    }
}

// Round 12
// 136.511 us; speedup vs baseline: 1.4622x; 1.0114x over previous
//
#include <hip/hip_runtime.h>
#include <hip/hip_bf16.h>
#include <hip/hip_fp16.h>

// Sparse gather-FFN. R11 (fp8) failed accuracy (0.031 > 0.0196) as the
// declared coin-flip risk; f16 RPB=8 is the anchor (main 77.5us).
// R12: latency probe. R7-R9 showed +-2e6 conflict-cycle swings move dur by
// ~0 -> DS pipe is NOT saturated; the loop is partly latency-exposed
// (load->wait->fma per 4-gather group at ~3.6 waves/SIMD). This round
// issues 8 independent ds_read_b128 per batch (2 batches/layer) before any
// FMA: in-flight depth 2x -> 8x. VGPR ~+32 (stays under the 5-block LDS
// occupancy cap). If dur doesn't move, DS is truly saturated and R10 is
// the structural ceiling.

#define NB   32768
#define NIN  128
#define NL   8
#define NW   256
#define NK   16
#define RPB  8                        // batch rows per block (8 f16 = 16 B)
#define STORED (NIN + (NL - 1) * NW)  // 1920 features ever re-read
#define NPARAM (NL * NW * NK)         // 32768 (l,u,k) entries

typedef __fp16 fp16v2 __attribute__((ext_vector_type(2)));

__device__ __forceinline__ unsigned pk16(float a, float b) {
    fp16v2 p = __builtin_amdgcn_cvt_pkrtz(a, b);   // v_cvt_pkrtz_f16_f32
    return __builtin_bit_cast(unsigned, p);
}

__device__ __forceinline__ __half2 as_h2(unsigned u) {
    return __builtin_bit_cast(__half2, u);
}

__device__ __forceinline__ float fast_sigmoid(float x) {
    return __builtin_amdgcn_rcpf(1.0f + __expf(-x));
}

// 8 row-MACs from one 16B packed-f16 word: 4x v_pk_fma_f16
__device__ __forceinline__ void fma_feat(__half2 acc[4], __half2 w2, uint4 p) {
    acc[0] = __hfma2(as_h2(p.x), w2, acc[0]);
    acc[1] = __hfma2(as_h2(p.y), w2, acc[1]);
    acc[2] = __hfma2(as_h2(p.z), w2, acc[2]);
    acc[3] = __hfma2(as_h2(p.w), w2, acc[3]);
}

template <bool PRE>
__global__ __launch_bounds__(256, 5)
void ffn_gather_kernel(const float* __restrict__ inputs,
                       const float* __restrict__ weights,
                       const float* __restrict__ biases,
                       const int*   __restrict__ edge_idx,
                       const int*   __restrict__ idxb,   // pre-scaled byte offs
                       const unsigned* __restrict__ wpk, // packed (w,w) f16
                       float* __restrict__ out)
{
    __shared__ uint4 vals[STORED];   // vals[f] = 8 f16 rows of feature f

    const int t = threadIdx.x;                       // 0..255, unit id
    const long long row0 = (long long)blockIdx.x * RPB;
    const char* vbase = (const char*)vals;

    // ---- stage the 128 input features for 8 rows (feature-major, f16) ----
    if (t < NIN) {
        float v[RPB];
        #pragma unroll
        for (int r = 0; r < RPB; ++r) v[r] = inputs[(row0 + r) * NIN + t];
        uint4 p;
        p.x = pk16(v[0], v[1]);
        p.y = pk16(v[2], v[3]);
        p.z = pk16(v[4], v[5]);
        p.w = pk16(v[6], v[7]);
        vals[t] = p;
    }
    __syncthreads();

    // ---- layers ----
    #pragma unroll
    for (int l = 0; l < NL; ++l) {
        const int base = (l * NW + t) * NK;

        const float b = biases[l * NW + t];
        __half2 acc[4];
        const __half2 bb = __float2half2_rn(b);
        #pragma unroll
        for (int j = 0; j < 4; ++j) acc[j] = bb;

        #pragma unroll
        for (int half = 0; half < 2; ++half) {
            const int hb = base + half * 8;
            int4 oA, oB;
            __half2 w[8];
            if (PRE) {
                oA = ((const int4*)(idxb + hb))[0];
                oB = ((const int4*)(idxb + hb))[1];
                const uint4 wA = ((const uint4*)(wpk + hb))[0];
                const uint4 wB = ((const uint4*)(wpk + hb))[1];
                w[0] = as_h2(wA.x); w[1] = as_h2(wA.y);
                w[2] = as_h2(wA.z); w[3] = as_h2(wA.w);
                w[4] = as_h2(wB.x); w[5] = as_h2(wB.y);
                w[6] = as_h2(wB.z); w[7] = as_h2(wB.w);
            } else {
                const int4 iA = ((const int4*)(edge_idx + hb))[0];
                const int4 iB = ((const int4*)(edge_idx + hb))[1];
                oA.x = iA.x << 4; oA.y = iA.y << 4;
                oA.z = iA.z << 4; oA.w = iA.w << 4;
                oB.x = iB.x << 4; oB.y = iB.y << 4;
                oB.z = iB.z << 4; oB.w = iB.w << 4;
                const float4 wA = ((const float4*)(weights + hb))[0];
                const float4 wB = ((const float4*)(weights + hb))[1];
                w[0] = __float2half2_rn(wA.x); w[1] = __float2half2_rn(wA.y);
                w[2] = __float2half2_rn(wA.z); w[3] = __float2half2_rn(wA.w);
                w[4] = __float2half2_rn(wB.x); w[5] = __float2half2_rn(wB.y);
                w[6] = __float2half2_rn(wB.z); w[7] = __float2half2_rn(wB.w);
            }
            // 8 independent LDS gathers in flight before any consumption
            uint4 p0 = *(const uint4*)(vbase + oA.x);
            uint4 p1 = *(const uint4*)(vbase + oA.y);
            uint4 p2 = *(const uint4*)(vbase + oA.z);
            uint4 p3 = *(const uint4*)(vbase + oA.w);
            uint4 p4 = *(const uint4*)(vbase + oB.x);
            uint4 p5 = *(const uint4*)(vbase + oB.y);
            uint4 p6 = *(const uint4*)(vbase + oB.z);
            uint4 p7 = *(const uint4*)(vbase + oB.w);
            fma_feat(acc, w[0], p0);
            fma_feat(acc, w[1], p1);
            fma_feat(acc, w[2], p2);
            fma_feat(acc, w[3], p3);
            fma_feat(acc, w[4], p4);
            fma_feat(acc, w[5], p5);
            fma_feat(acc, w[6], p6);
            fma_feat(acc, w[7], p7);
        }

        float s[RPB];
        #pragma unroll
        for (int j = 0; j < 4; ++j) {
            s[2 * j + 0] = fast_sigmoid(__low2float(acc[j]));
            s[2 * j + 1] = fast_sigmoid(__high2float(acc[j]));
        }

        if (l < NL - 1) {
            uint4 p;
            p.x = pk16(s[0], s[1]);
            p.y = pk16(s[2], s[3]);
            p.z = pk16(s[4], s[5]);
            p.w = pk16(s[6], s[7]);
            vals[NIN + l * NW + t] = p;
            __syncthreads();
        } else {
            #pragma unroll
            for (int r = 0; r < RPB; ++r)
                out[(row0 + r) * NW + t] = s[r];
        }
    }
}

// trivial pre-pass: byte-offset indices + packed (w,w) f16 weights.
__global__ __launch_bounds__(256)
void prepass_kernel(const float* __restrict__ weights,
                    const int* __restrict__ edge_idx,
                    int* __restrict__ idxb,
                    unsigned* __restrict__ wpk)
{
    const int i = blockIdx.x * 256 + threadIdx.x;   // 0..32767
    idxb[i] = edge_idx[i] << 4;
    const float w = weights[i];
    wpk[i] = pk16(w, w);
}

extern "C" void kernel_launch(void* const* d_in, const int* in_sizes, int n_in,
                              void* d_out, int out_size, void* d_ws, size_t ws_size,
                              hipStream_t stream)
{
    const float* inputs   = (const float*)d_in[0];
    const float* weights  = (const float*)d_in[1];
    const float* biases   = (const float*)d_in[2];
    const int*   edge_idx = (const int*)d_in[3];
    float* out = (float*)d_out;

    dim3 grid(NB / RPB);   // 4096
    dim3 block(NW);        // 256

    const size_t need = (size_t)NPARAM * 4 * 2;     // 256 KB
    if (ws_size >= need) {
        int*      idxb = (int*)d_ws;
        unsigned* wpk  = (unsigned*)((char*)d_ws + (size_t)NPARAM * 4);
        prepass_kernel<<<NPARAM / 256, 256, 0, stream>>>(weights, edge_idx,
                                                         idxb, wpk);
        ffn_gather_kernel<true><<<grid, block, 0, stream>>>(
            inputs, weights, biases, edge_idx, idxb, wpk, out);
    } else {
        ffn_gather_kernel<false><<<grid, block, 0, stream>>>(
            inputs, weights, biases, edge_idx, nullptr, nullptr, out);
    }
}

// Round 13
// 133.557 us; speedup vs baseline: 1.4946x; 1.0221x over previous
//
#include <hip/hip_runtime.h>
#include <hip/hip_bf16.h>
#include <hip/hip_fp16.h>

// Sparse gather-FFN. Plateau analysis (R10-R12): main ~76.5us, DS pipe ~89%
// busy (8192 wave ds_read_b128/CU x ~12cyc + 27us conflicts), VALU 27us
// hidden, ~8-10us barrier/tail residual. Compiler already max-hoists gathers
// (R12: VGPR unchanged at 48).
// R13: two 8-row groups per block (RPB=16, valsA/valsB, 61.4KB LDS,
// 2 blocks/CU). Each thread loads idx/w ONCE per quartet and serves both
// groups (2x work per index fetch, 8 independent b128s in flight), and one
// barrier now serves 16 rows -> barrier drains per row halve. Total DS
// reads unchanged. Risk: occupancy 5->2 blocks/CU may open DS-issue gaps.

#define NB   32768
#define NIN  128
#define NL   8
#define NW   256
#define NK   16
#define RPB  16                       // rows per block = 2 groups x 8
#define STORED (NIN + (NL - 1) * NW)  // 1920 features per group
#define NPARAM (NL * NW * NK)         // 32768 (l,u,k) entries

typedef __fp16 fp16v2 __attribute__((ext_vector_type(2)));

__device__ __forceinline__ unsigned pk16(float a, float b) {
    fp16v2 p = __builtin_amdgcn_cvt_pkrtz(a, b);   // v_cvt_pkrtz_f16_f32
    return __builtin_bit_cast(unsigned, p);
}

__device__ __forceinline__ __half2 as_h2(unsigned u) {
    return __builtin_bit_cast(__half2, u);
}

__device__ __forceinline__ float fast_sigmoid(float x) {
    return __builtin_amdgcn_rcpf(1.0f + __expf(-x));
}

// 8 row-MACs from one 16B packed-f16 word: 4x v_pk_fma_f16
__device__ __forceinline__ void fma_feat(__half2 acc[4], __half2 w2, uint4 p) {
    acc[0] = __hfma2(as_h2(p.x), w2, acc[0]);
    acc[1] = __hfma2(as_h2(p.y), w2, acc[1]);
    acc[2] = __hfma2(as_h2(p.z), w2, acc[2]);
    acc[3] = __hfma2(as_h2(p.w), w2, acc[3]);
}

template <bool PRE>
__global__ __launch_bounds__(256, 2)
void ffn_gather_kernel(const float* __restrict__ inputs,
                       const float* __restrict__ weights,
                       const float* __restrict__ biases,
                       const int*   __restrict__ edge_idx,
                       const int*   __restrict__ idxb,   // pre-scaled byte offs
                       const unsigned* __restrict__ wpk, // packed (w,w) f16
                       float* __restrict__ out)
{
    __shared__ uint4 valsA[STORED];   // group A: rows row0..row0+7
    __shared__ uint4 valsB[STORED];   // group B: rows row0+8..row0+15

    const int t = threadIdx.x;                       // 0..255, unit id
    const long long row0 = (long long)blockIdx.x * RPB;
    const char* vbaseA = (const char*)valsA;
    const char* vbaseB = (const char*)valsB;

    // ---- stage 128 input features x 16 rows: t<128 -> A, t>=128 -> B ----
    {
        const int f = t & 127;
        const long long r0 = row0 + ((t >> 7) << 3);   // +0 (A) or +8 (B)
        float v[8];
        #pragma unroll
        for (int r = 0; r < 8; ++r) v[r] = inputs[(r0 + r) * NIN + f];
        uint4 p;
        p.x = pk16(v[0], v[1]);
        p.y = pk16(v[2], v[3]);
        p.z = pk16(v[4], v[5]);
        p.w = pk16(v[6], v[7]);
        if (t < NIN) valsA[f] = p; else valsB[f] = p;
    }
    __syncthreads();

    // ---- layers ----
    #pragma unroll
    for (int l = 0; l < NL; ++l) {
        const int base = (l * NW + t) * NK;

        const float b = biases[l * NW + t];
        __half2 accA[4], accB[4];
        const __half2 bb = __float2half2_rn(b);
        #pragma unroll
        for (int j = 0; j < 4; ++j) { accA[j] = bb; accB[j] = bb; }

        #pragma unroll
        for (int kk = 0; kk < NK / 4; ++kk) {
            int4 o4;          // byte offsets into vals (shared by A and B!)
            __half2 w0, w1, w2, w3;
            if (PRE) {
                o4 = ((const int4*)(idxb + base))[kk];
                uint4 wp = ((const uint4*)(wpk + base))[kk];
                w0 = as_h2(wp.x); w1 = as_h2(wp.y);
                w2 = as_h2(wp.z); w3 = as_h2(wp.w);
            } else {
                int4 i4 = ((const int4*)(edge_idx + base))[kk];
                o4.x = i4.x << 4; o4.y = i4.y << 4;
                o4.z = i4.z << 4; o4.w = i4.w << 4;
                float4 w4 = ((const float4*)(weights + base))[kk];
                w0 = __float2half2_rn(w4.x);
                w1 = __float2half2_rn(w4.y);
                w2 = __float2half2_rn(w4.z);
                w3 = __float2half2_rn(w4.w);
            }
            // 8 independent gathers (two per feature, groups A+B)
            const uint4 a0 = *(const uint4*)(vbaseA + o4.x);
            const uint4 b0 = *(const uint4*)(vbaseB + o4.x);
            const uint4 a1 = *(const uint4*)(vbaseA + o4.y);
            const uint4 b1 = *(const uint4*)(vbaseB + o4.y);
            const uint4 a2 = *(const uint4*)(vbaseA + o4.z);
            const uint4 b2 = *(const uint4*)(vbaseB + o4.z);
            const uint4 a3 = *(const uint4*)(vbaseA + o4.w);
            const uint4 b3 = *(const uint4*)(vbaseB + o4.w);
            fma_feat(accA, w0, a0);
            fma_feat(accB, w0, b0);
            fma_feat(accA, w1, a1);
            fma_feat(accB, w1, b1);
            fma_feat(accA, w2, a2);
            fma_feat(accB, w2, b2);
            fma_feat(accA, w3, a3);
            fma_feat(accB, w3, b3);
        }

        float sA[8], sB[8];
        #pragma unroll
        for (int j = 0; j < 4; ++j) {
            sA[2 * j + 0] = fast_sigmoid(__low2float(accA[j]));
            sA[2 * j + 1] = fast_sigmoid(__high2float(accA[j]));
            sB[2 * j + 0] = fast_sigmoid(__low2float(accB[j]));
            sB[2 * j + 1] = fast_sigmoid(__high2float(accB[j]));
        }

        if (l < NL - 1) {
            uint4 pA, pB;
            pA.x = pk16(sA[0], sA[1]); pA.y = pk16(sA[2], sA[3]);
            pA.z = pk16(sA[4], sA[5]); pA.w = pk16(sA[6], sA[7]);
            pB.x = pk16(sB[0], sB[1]); pB.y = pk16(sB[2], sB[3]);
            pB.z = pk16(sB[4], sB[5]); pB.w = pk16(sB[6], sB[7]);
            valsA[NIN + l * NW + t] = pA;
            valsB[NIN + l * NW + t] = pB;
            __syncthreads();           // ONE barrier per 16 rows per layer
        } else {
            #pragma unroll
            for (int r = 0; r < 8; ++r) {
                out[(row0 + r) * NW + t]     = sA[r];
                out[(row0 + 8 + r) * NW + t] = sB[r];
            }
        }
    }
}

// trivial pre-pass: byte-offset indices + packed (w,w) f16 weights.
__global__ __launch_bounds__(256)
void prepass_kernel(const float* __restrict__ weights,
                    const int* __restrict__ edge_idx,
                    int* __restrict__ idxb,
                    unsigned* __restrict__ wpk)
{
    const int i = blockIdx.x * 256 + threadIdx.x;   // 0..32767
    idxb[i] = edge_idx[i] << 4;
    const float w = weights[i];
    wpk[i] = pk16(w, w);
}

extern "C" void kernel_launch(void* const* d_in, const int* in_sizes, int n_in,
                              void* d_out, int out_size, void* d_ws, size_t ws_size,
                              hipStream_t stream)
{
    const float* inputs   = (const float*)d_in[0];
    const float* weights  = (const float*)d_in[1];
    const float* biases   = (const float*)d_in[2];
    const int*   edge_idx = (const int*)d_in[3];
    float* out = (float*)d_out;

    dim3 grid(NB / RPB);   // 2048
    dim3 block(NW);        // 256

    const size_t need = (size_t)NPARAM * 4 * 2;     // 256 KB
    if (ws_size >= need) {
        int*      idxb = (int*)d_ws;
        unsigned* wpk  = (unsigned*)((char*)d_ws + (size_t)NPARAM * 4);
        prepass_kernel<<<NPARAM / 256, 256, 0, stream>>>(weights, edge_idx,
                                                         idxb, wpk);
        ffn_gather_kernel<true><<<grid, block, 0, stream>>>(
            inputs, weights, biases, edge_idx, idxb, wpk, out);
    } else {
        ffn_gather_kernel<false><<<grid, block, 0, stream>>>(
            inputs, weights, biases, edge_idx, nullptr, nullptr, out);
    }
}